// Round 11
// baseline (1133.816 us; speedup 1.0000x reference)
//
#include <hip/hip_runtime.h>
#include <hip/hip_bf16.h>
#include <math.h>

#define NB 16
#define NPT 4096
#define NS 1024
#define NK 64
#define CNTF 1048576.0f
#define R2C 0.04f
#define BNEPS 1e-5f

// ws float offsets
#define OFF_NEWXYZ 0
#define OFF_X1     49152
#define OFF_STATS  6340608           // 32 copies x ST_LEN
#define NCOPY 32
#define ST_LEN 8352
#define OFF_FOLD   6607872           // 6340608 + 32*8352
#define ST_M1 0
#define ST_G1 6
#define ST_M2 27
#define ST_G2 91
#define ST_M3 4187
#define ST_G3 4251
#define F_W0 0
#define F_B0 384
#define F_W1 448
#define F_B1 4544
#define F_W2 4608
#define F_B2 12800
#define OUTC_OFF 2097152

typedef __attribute__((ext_vector_type(8))) short s8v;
typedef __attribute__((ext_vector_type(4))) short s4v;
typedef __attribute__((ext_vector_type(4))) float f4v;

__device__ __forceinline__ float bf2f(short s) {
  return __uint_as_float(((unsigned)(unsigned short)s) << 16);
}
__device__ __forceinline__ short f2bf(float f) {
  unsigned u = __float_as_uint(f);
  return (short)((u + 0x7fff + ((u >> 16) & 1)) >> 16);
}
__device__ __forceinline__ int SW(int p) {
  return (((p) & 7) << 1) | (((p) >> 3) & 1);
}
__device__ __forceinline__ f4v mm(s8v a, s8v b, f4v c) {
  return __builtin_amdgcn_mfma_f32_16x16x32_bf16(a, b, c, 0, 0, 0);
}
__device__ __forceinline__ s8v ldB_pc(const short* x, int t, int l, int kb) {
  int p = t * 16 + (l & 15);
  int c0 = kb + 4 * (l >> 4);
  int base = p << 6;
  s4v a = *(const s4v*)&x[base + ((((c0) >> 2) ^ SW(p)) << 2)];
  s4v b = *(const s4v*)&x[base + ((((c0 + 16) >> 2) ^ SW(p)) << 2)];
  s8v r; r[0]=a[0]; r[1]=a[1]; r[2]=a[2]; r[3]=a[3]; r[4]=b[0]; r[5]=b[1]; r[6]=b[2]; r[7]=b[3];
  return r;
}
__device__ __forceinline__ s8v ldG_cp(const short* x, int ct, int l, int pb) {
  int c = ct * 16 + (l & 15);
  int p0 = pb + 4 * (l >> 4);
  int base = c << 6;
  s4v a = *(const s4v*)&x[base + ((((p0) >> 2) ^ SW(c)) << 2)];
  s4v b = *(const s4v*)&x[base + ((((p0 + 16) >> 2) ^ SW(c)) << 2)];
  s8v r; r[0]=a[0]; r[1]=a[1]; r[2]=a[2]; r[3]=a[3]; r[4]=b[0]; r[5]=b[1]; r[6]=b[2]; r[7]=b[3];
  return r;
}
__device__ __forceinline__ s8v mkWfrag(const float* W, int row, int kb, int l) {
  int c0 = kb + 4 * (l >> 4);
  s8v f;
#pragma unroll
  for (int j = 0; j < 4; ++j) f[j] = f2bf(W[row * 64 + c0 + j]);
#pragma unroll
  for (int j = 0; j < 4; ++j) f[4 + j] = f2bf(W[row * 64 + c0 + 16 + j]);
  return f;
}
__device__ __forceinline__ s8v onesfrag() {
  s8v f;
#pragma unroll
  for (int j = 0; j < 8; ++j) f[j] = (short)0x3F80;
  return f;
}
__device__ __forceinline__ float rowmax16(float x) {
#define DPPMAX(ctrl)                                                          \
  x = fmaxf(x, __int_as_float(__builtin_amdgcn_update_dpp(                    \
             0, __float_as_int(x), ctrl, 0xf, 0xf, true)))
  DPPMAX(0x111); DPPMAX(0x112); DPPMAX(0x114); DPPMAX(0x118);
#undef DPPMAX
  return x;
}
// full wave64 max; result valid in lane 63 (bound_ctrl zero-fill safe: x >= 0)
__device__ __forceinline__ float wave64max(float x) {
#define DPPMAX(ctrl)                                                          \
  x = fmaxf(x, __int_as_float(__builtin_amdgcn_update_dpp(                    \
             0, __float_as_int(x), ctrl, 0xf, 0xf, true)))
  DPPMAX(0x111); DPPMAX(0x112); DPPMAX(0x114); DPPMAX(0x118);
  DPPMAX(0x142);  // row_bcast:15
  DPPMAX(0x143);  // row_bcast:31
#undef DPPMAX
  return x;
}

// ---------------- FPS: 512 thr, issue-minimal reduction ----------------------
// Active-CU VALUBusy was ~83% (issue-bound): cut per-lane instructions.
// Update tracks only dd[] + running bv (no nd copy). Wave max = 6 DPP ops +
// ONE readlane(63). Winner xyz extracted ONLY in the lead lane's exec-masked
// branch (21 cndmasks once per wave, not per lane). Tie-breaks unchanged:
// ballot+ctz lowest lane; ascending strict-> scan across waves.
__launch_bounds__(512)
__global__ void k_fps(const float* __restrict__ coord, float* __restrict__ newxyz,
                      float* __restrict__ out_coord) {
#pragma clang fp contract(off)
  __shared__ float4 sxyz[NPT];
  __shared__ float4 snew[NS];
  __shared__ uint4 skey[2][8];   // dist_bits, x_bits, y_bits, z_bits
  int b = blockIdx.x;
  int tid = threadIdx.x;
  int w = tid >> 6, lane = tid & 63;
  const float* cb = coord + (size_t)b * 3 * NPT;
  for (int i = tid; i < NPT; i += 512)
    sxyz[i] = make_float4(cb[i], cb[NPT + i], cb[2 * NPT + i], 0.f);
  __syncthreads();
  float px[8], py[8], pz[8], dd[8];
  int base = tid * 8;
#pragma unroll
  for (int j = 0; j < 8; ++j) {
    float4 p = sxyz[base + j];
    px[j] = p.x; py[j] = p.y; pz[j] = p.z; dd[j] = 1e10f;
    asm volatile("" : "+v"(px[j]), "+v"(py[j]), "+v"(pz[j]));
  }
  float4 c0 = sxyz[0];
  float cx = c0.x, cy = c0.y, cz = c0.z;
  if (tid == 0) snew[0] = make_float4(cx, cy, cz, 0.f);
  for (int it = 1; it < NS; ++it) {
    float bv;
#pragma unroll
    for (int j = 0; j < 8; ++j) {
      float dx = px[j] - cx, dy = py[j] - cy, dz = pz[j] - cz;
      float d = dx * dx; d = d + dy * dy; d = d + dz * dz;
      float v = fminf(dd[j], d); dd[j] = v;
      bv = (j == 0) ? v : fmaxf(bv, v);
    }
    float rm = wave64max(bv);
    float wmax = __int_as_float(__builtin_amdgcn_readlane(__float_as_int(rm), 63));
    unsigned long long mmk = __ballot(bv == wmax);
    int lead = (int)__builtin_ctzll(mmk);
    int par = it & 1;
    if (lane == lead) {
      // first-occurrence winner xyz (dd == post-update distances), static idx
      float wx = px[7], wy = py[7], wz = pz[7];
#pragma unroll
      for (int j = 6; j >= 0; --j) {
        bool t = (dd[j] == bv);
        wx = t ? px[j] : wx;
        wy = t ? py[j] : wy;
        wz = t ? pz[j] : wz;
      }
      skey[par][w] = make_uint4(__float_as_uint(bv), __float_as_uint(wx),
                                __float_as_uint(wy), __float_as_uint(wz));
    }
    __syncthreads();
    uint4 e0 = skey[par][0];
    unsigned kb_ = e0.x, xb = e0.y, yb = e0.z, zb = e0.w;
#pragma unroll
    for (int q = 1; q < 8; ++q) {
      uint4 e = skey[par][q];
      bool s = e.x > kb_;           // strict >: lowest wave wins ties
      kb_ = s ? e.x : kb_;
      xb = s ? e.y : xb; yb = s ? e.z : yb; zb = s ? e.w : zb;
    }
    cx = __uint_as_float(xb);
    cy = __uint_as_float(yb);
    cz = __uint_as_float(zb);
    if (tid == 0) snew[it] = make_float4(cx, cy, cz, 0.f);
  }
  __syncthreads();
  for (int s = tid; s < NS; s += 512) {
    float4 p = snew[s];
    newxyz[((size_t)b * NS + s) * 3 + 0] = p.x;
    newxyz[((size_t)b * NS + s) * 3 + 1] = p.y;
    newxyz[((size_t)b * NS + s) * 3 + 2] = p.z;
    out_coord[((size_t)b * 3 + 0) * NS + s] = p.x;
    out_coord[((size_t)b * 3 + 1) * NS + s] = p.y;
    out_coord[((size_t)b * 3 + 2) * NS + s] = p.z;
  }
}

// ------------- Ball query + grouping (prefetch-pipelined) --------------------
__launch_bounds__(256)
__global__ void k_group(const float* __restrict__ coord, const float* __restrict__ feat,
                        const float* __restrict__ newxyz, float* __restrict__ x1) {
#pragma clang fp contract(off)
  __shared__ float st[4][6][64];
  int tid = threadIdx.x;
  int w = tid >> 6, lane = tid & 63;
  int g = blockIdx.x * 4 + w;
  int b = g >> 10;
  const float* cb = coord + (size_t)b * 3 * NPT;
  const float* fb = feat + (size_t)b * 3 * NPT;
  float cx = newxyz[(size_t)g * 3 + 0], cy = newxyz[(size_t)g * 3 + 1], cz = newxyz[(size_t)g * 3 + 2];
  int cnt = 0;
  float x = cb[lane], y = cb[NPT + lane], z = cb[2 * NPT + lane];
  for (int ch = 0; ch < NPT / 64 && cnt < 64; ++ch) {
    float xn = 0.f, yn = 0.f, zn = 0.f;
    if (ch + 1 < NPT / 64) {
      int pn = (ch + 1) * 64 + lane;
      xn = cb[pn]; yn = cb[NPT + pn]; zn = cb[2 * NPT + pn];
    }
    int p = ch * 64 + lane;
    float dx = x - cx, dy = y - cy, dz = z - cz;
    float d = dx * dx; d = d + dy * dy; d = d + dz * dz;
    bool in = (d <= R2C);
    unsigned long long m = __ballot(in);
    int rank = __popcll(m & ((1ull << lane) - 1ull));
    int slot = cnt + rank;
    if (in && slot < 64) {
      st[w][0][slot] = dx; st[w][1][slot] = dy; st[w][2][slot] = dz;
      st[w][3][slot] = fb[p]; st[w][4][slot] = fb[NPT + p]; st[w][5][slot] = fb[2 * NPT + p];
    }
    cnt += (int)__popcll(m);
    x = xn; y = yn; z = zn;
  }
  __syncthreads();
  cnt = min(cnt, 64);
  if (lane >= cnt) {
#pragma unroll
    for (int c = 0; c < 6; ++c) st[w][c][lane] = st[w][c][0];
  }
  float* dst = x1 + (size_t)g * 384;
#pragma unroll
  for (int c = 0; c < 6; ++c) dst[c * 64 + lane] = st[w][c][lane];
}

// ---------------- stats of x1 (f32 exact, 32-copy partials) ------------------
__launch_bounds__(256)
__global__ void k_stats1(const float* __restrict__ x1, float* __restrict__ stats) {
  float* st = stats + (size_t)(blockIdx.x & (NCOPY - 1)) * ST_LEN;
  float m[6] = {0, 0, 0, 0, 0, 0};
  float gacc[21];
#pragma unroll
  for (int q = 0; q < 21; ++q) gacc[q] = 0.f;
  int nth = gridDim.x * 256;
  for (int col = blockIdx.x * 256 + threadIdx.x; col < NB * NS * NK; col += nth) {
    int g = col >> 6, k = col & 63;
    const float* p = x1 + (size_t)g * 384;
    float v[6];
#pragma unroll
    for (int c = 0; c < 6; ++c) v[c] = p[c * 64 + k];
    int q = 0;
#pragma unroll
    for (int c = 0; c < 6; ++c) {
      m[c] += v[c];
#pragma unroll
      for (int c2 = c; c2 < 6; ++c2) { gacc[q] += v[c] * v[c2]; q++; }
    }
  }
#pragma unroll
  for (int c = 0; c < 6; ++c) {
    float t = m[c];
    for (int o = 1; o < 64; o <<= 1) t += __shfl_xor(t, o);
    if ((threadIdx.x & 63) == 0) atomicAdd(&st[ST_M1 + c], t);
  }
#pragma unroll
  for (int q = 0; q < 21; ++q) {
    float t = gacc[q];
    for (int o = 1; o < 64; o <<= 1) t += __shfl_xor(t, o);
    if ((threadIdx.x & 63) == 0) atomicAdd(&st[ST_G1 + q], t);
  }
}

// ---------------- fold kernels (sum 32 copies, then fold) --------------------
__launch_bounds__(256)
__global__ void k_fold1(const float* __restrict__ W0, const float* __restrict__ b0,
                        const float* __restrict__ g0, const float* __restrict__ be0,
                        const float* __restrict__ stats, float* __restrict__ fold) {
  __shared__ float sMG[27];
  int tid = threadIdx.x;
  if (tid < 27) {
    float s = 0.f;
    for (int cp = 0; cp < NCOPY; ++cp) s += stats[(size_t)cp * ST_LEN + tid];
    sMG[tid] = s;
  }
  __syncthreads();
  int o = tid;
  if (o >= 64) return;
  float G[6][6], mu[6];
  {
    int q = 0;
    for (int c = 0; c < 6; ++c)
      for (int c2 = c; c2 < 6; ++c2) { float v = sMG[ST_G1 + q] / CNTF; G[c][c2] = v; G[c2][c] = v; q++; }
    for (int c = 0; c < 6; ++c) mu[c] = sMG[ST_M1 + c] / CNTF;
  }
  float w[6];
  for (int c = 0; c < 6; ++c) w[c] = W0[o * 6 + c];
  float bb = b0[o];
  float s1 = 0.f, ey2 = 0.f;
  for (int c = 0; c < 6; ++c) {
    s1 += w[c] * mu[c];
    for (int c2 = 0; c2 < 6; ++c2) ey2 += w[c] * w[c2] * G[c][c2];
  }
  float muy = s1 + bb;
  ey2 = ey2 + 2.f * bb * s1 + bb * bb;
  float var = ey2 - muy * muy;
  float sc = g0[o] / sqrtf(var + BNEPS);
  for (int c = 0; c < 6; ++c) fold[F_W0 + o * 6 + c] = w[c] * sc;
  fold[F_B0 + o] = (bb - muy) * sc + be0[o];
}

__launch_bounds__(256)
__global__ void k_fold2(const float* __restrict__ W1, const float* __restrict__ b1,
                        const float* __restrict__ g1, const float* __restrict__ be1,
                        const float* __restrict__ stats, float* __restrict__ fold) {
  __shared__ float sG[4096];
  __shared__ float sM[64];
  int tid = threadIdx.x;
  for (int i = tid; i < 4096; i += 256) {
    float s = 0.f;
    for (int cp = 0; cp < NCOPY; ++cp) s += stats[(size_t)cp * ST_LEN + ST_G2 + i];
    sG[i] = s;
  }
  if (tid < 64) {
    float s = 0.f;
    for (int cp = 0; cp < NCOPY; ++cp) s += stats[(size_t)cp * ST_LEN + ST_M2 + tid];
    sM[tid] = s;
  }
  __syncthreads();
  int o = tid;
  if (o >= 64) return;
  float s1 = 0.f, ey2 = 0.f;
  for (int c = 0; c < 64; ++c) {
    float w = W1[o * 64 + c];
    s1 += w * sM[c];
    float t = 0.f;
    for (int c2 = 0; c2 < 64; ++c2) t += W1[o * 64 + c2] * sG[c * 64 + c2];
    ey2 += w * t;
  }
  s1 /= CNTF; ey2 /= CNTF;
  float bb = b1[o];
  float muy = s1 + bb;
  ey2 = ey2 + 2.f * bb * s1 + bb * bb;
  float var = ey2 - muy * muy;
  float sc = g1[o] / sqrtf(var + BNEPS);
  for (int c = 0; c < 64; ++c) fold[F_W1 + o * 64 + c] = W1[o * 64 + c] * sc;
  fold[F_B1 + o] = (bb - muy) * sc + be1[o];
}

__launch_bounds__(256)
__global__ void k_fold3(const float* __restrict__ W2, const float* __restrict__ b2,
                        const float* __restrict__ g2, const float* __restrict__ be2,
                        const float* __restrict__ stats, float* __restrict__ fold) {
  __shared__ float sG[4096];
  __shared__ float sM[64];
  int tid = threadIdx.x;
  for (int i = tid; i < 4096; i += 256) {
    float s = 0.f;
    for (int cp = 0; cp < NCOPY; ++cp) s += stats[(size_t)cp * ST_LEN + ST_G3 + i];
    sG[i] = s;
  }
  if (tid < 64) {
    float s = 0.f;
    for (int cp = 0; cp < NCOPY; ++cp) s += stats[(size_t)cp * ST_LEN + ST_M3 + tid];
    sM[tid] = s;
  }
  __syncthreads();
  int o = tid;
  if (o >= 128) return;
  float s1 = 0.f, ey2 = 0.f;
  for (int c = 0; c < 64; ++c) {
    float w = W2[o * 64 + c];
    s1 += w * sM[c];
    float t = 0.f;
    for (int c2 = 0; c2 < 64; ++c2) t += W2[o * 64 + c2] * sG[c * 64 + c2];
    ey2 += w * t;
  }
  s1 /= CNTF; ey2 /= CNTF;
  float bb = b2[o];
  float muy = s1 + bb;
  ey2 = ey2 + 2.f * bb * s1 + bb * bb;
  float var = ey2 - muy * muy;
  float sc = g2[o] / sqrtf(var + BNEPS);
  for (int c = 0; c < 64; ++c) fold[F_W2 + o * 64 + c] = W2[o * 64 + c] * sc;
  fold[F_B2 + o] = (bb - muy) * sc + be2[o];
}

// conv1 (f32) -> x2 bf16 into [p][c] layout (swizzled)
__device__ __forceinline__ void x2_to_pc(const float* x1s, const float* wf0, const float* bf0,
                                         short* x2p, int tid) {
  int p = tid & 63, r = tid >> 6;
  float xin[6];
#pragma unroll
  for (int c = 0; c < 6; ++c) xin[c] = x1s[c * 64 + p];
#pragma unroll
  for (int m4 = 0; m4 < 4; ++m4) {
    s4v v;
#pragma unroll
    for (int u = 0; u < 4; ++u) {
      int o = r * 16 + m4 * 4 + u;
      float a = bf0[o];
#pragma unroll
      for (int c = 0; c < 6; ++c) a += wf0[o * 6 + c] * xin[c];
      v[u] = f2bf(fmaxf(a, 0.f));
    }
    int cb = r * 16 + m4 * 4;
    *(s4v*)&x2p[(p << 6) + (((cb >> 2) ^ SW(p)) << 2)] = v;
  }
}
// conv1 (f32) -> x2 bf16 into [c][p] layout (swizzled)
__device__ __forceinline__ void x2_to_cp(const float* x1s, const float* wf0, const float* bf0,
                                         short* x2c, int tid) {
  int p = tid & 63, r = tid >> 6;
  float xin[6];
#pragma unroll
  for (int c = 0; c < 6; ++c) xin[c] = x1s[c * 64 + p];
#pragma unroll
  for (int i = 0; i < 16; ++i) {
    int o = r * 16 + i;
    float a = bf0[o];
#pragma unroll
    for (int c = 0; c < 6; ++c) a += wf0[o * 6 + c] * xin[c];
    x2c[(o << 6) + (((p >> 2) ^ SW(o)) << 2) + (p & 3)] = f2bf(fmaxf(a, 0.f));
  }
}

// ---------------- pass2: x2 stats via MFMA gram + ones-mean ------------------
__launch_bounds__(256)
__global__ void k_pass2(const float* __restrict__ x1, const float* __restrict__ fold,
                        float* __restrict__ stats) {
  __shared__ float x1s[384];
  __shared__ float wf0s[384];
  __shared__ float bf0s[64];
  __shared__ short x2c[4096];
  int tid = threadIdx.x;
  int lane = tid & 63, w = tid >> 6;
  float* st = stats + (size_t)(blockIdx.x & (NCOPY - 1)) * ST_LEN;
  for (int i = tid; i < 384; i += 256) wf0s[i] = fold[F_W0 + i];
  if (tid < 64) bf0s[tid] = fold[F_B0 + tid];
  s8v ones = onesfrag();
  f4v gacc[4] = {};
  f4v maccv = {};
  for (int rep = 0; rep < 32; ++rep) {
    int g = blockIdx.x + rep * 512;
    __syncthreads();
    for (int i = tid; i < 384; i += 256) x1s[i] = x1[(size_t)g * 384 + i];
    __syncthreads();
    x2_to_cp(x1s, wf0s, bf0s, x2c, tid);
    __syncthreads();
#pragma unroll
    for (int pb = 0; pb < 64; pb += 32) {
      s8v a = ldG_cp(x2c, w, lane, pb);
      maccv = mm(a, ones, maccv);
#pragma unroll
      for (int ct = 0; ct < 4; ++ct)
        gacc[ct] = mm(a, ldG_cp(x2c, ct, lane, pb), gacc[ct]);
    }
  }
#pragma unroll
  for (int ct = 0; ct < 4; ++ct)
#pragma unroll
    for (int r = 0; r < 4; ++r) {
      int row = 16 * w + 4 * (lane >> 4) + r;
      int col = 16 * ct + (lane & 15);
      atomicAdd(&st[ST_G2 + row * 64 + col], gacc[ct][r]);
    }
  if ((lane & 15) == 0)
#pragma unroll
    for (int r = 0; r < 4; ++r)
      atomicAdd(&st[ST_M2 + 16 * w + 4 * (lane >> 4) + r], maccv[r]);
}

// ---------------- pass3: x3 stats via MFMA conv2 + gram + ones-mean ----------
__launch_bounds__(256)
__global__ void k_pass3(const float* __restrict__ x1, const float* __restrict__ fold,
                        float* __restrict__ stats) {
  __shared__ float x1s[384];
  __shared__ float wf0s[384];
  __shared__ float bf0s[64];
  __shared__ short x2p[4096];
  __shared__ short x3c[4096];
  int tid = threadIdx.x;
  int lane = tid & 63, w = tid >> 6;
  float* st = stats + (size_t)(blockIdx.x & (NCOPY - 1)) * ST_LEN;
  for (int i = tid; i < 384; i += 256) wf0s[i] = fold[F_W0 + i];
  if (tid < 64) bf0s[tid] = fold[F_B0 + tid];
  s8v w1f[2];
  float bias2[4];
#pragma unroll
  for (int s = 0; s < 2; ++s) w1f[s] = mkWfrag(fold + F_W1, 16 * w + (lane & 15), 32 * s, lane);
#pragma unroll
  for (int r = 0; r < 4; ++r) bias2[r] = fold[F_B1 + 16 * w + 4 * (lane >> 4) + r];
  s8v ones = onesfrag();
  f4v gacc[4] = {};
  f4v maccv = {};
  for (int rep = 0; rep < 32; ++rep) {
    int g = blockIdx.x + rep * 512;
    __syncthreads();
    for (int i = tid; i < 384; i += 256) x1s[i] = x1[(size_t)g * 384 + i];
    __syncthreads();
    x2_to_pc(x1s, wf0s, bf0s, x2p, tid);
    __syncthreads();
#pragma unroll
    for (int t = 0; t < 4; ++t) {
      f4v acc; acc[0] = bias2[0]; acc[1] = bias2[1]; acc[2] = bias2[2]; acc[3] = bias2[3];
      acc = mm(w1f[0], ldB_pc(x2p, t, lane, 0), acc);
      acc = mm(w1f[1], ldB_pc(x2p, t, lane, 32), acc);
      int p = 16 * t + (lane & 15);
#pragma unroll
      for (int r = 0; r < 4; ++r) {
        int c = 16 * w + 4 * (lane >> 4) + r;
        x3c[(c << 6) + (((p >> 2) ^ SW(c)) << 2) + (p & 3)] = f2bf(fmaxf(acc[r], 0.f));
      }
    }
    __syncthreads();
#pragma unroll
    for (int pb = 0; pb < 64; pb += 32) {
      s8v a = ldG_cp(x3c, w, lane, pb);
      maccv = mm(a, ones, maccv);
#pragma unroll
      for (int ct = 0; ct < 4; ++ct)
        gacc[ct] = mm(a, ldG_cp(x3c, ct, lane, pb), gacc[ct]);
    }
  }
#pragma unroll
  for (int ct = 0; ct < 4; ++ct)
#pragma unroll
    for (int r = 0; r < 4; ++r) {
      int row = 16 * w + 4 * (lane >> 4) + r;
      int col = 16 * ct + (lane & 15);
      atomicAdd(&st[ST_G3 + row * 64 + col], gacc[ct][r]);
    }
  if ((lane & 15) == 0)
#pragma unroll
    for (int r = 0; r < 4; ++r)
      atomicAdd(&st[ST_M3 + 16 * w + 4 * (lane >> 4) + r], maccv[r]);
}

// ---------------- final: conv2+conv3 MFMA + k-max ----------------------------
__launch_bounds__(256)
__global__ void k_final(const float* __restrict__ x1, const float* __restrict__ fold,
                        float* __restrict__ out) {
  __shared__ float x1s[384];
  __shared__ float wf0s[384];
  __shared__ float bf0s[64];
  __shared__ short x2p[4096];
  __shared__ short x3p[4096];
  int tid = threadIdx.x;
  int lane = tid & 63, w = tid >> 6;
  for (int i = tid; i < 384; i += 256) wf0s[i] = fold[F_W0 + i];
  if (tid < 64) bf0s[tid] = fold[F_B0 + tid];
  s8v w1f[2], w2f[2][2];
  float bias2[4], bias3[2][4];
#pragma unroll
  for (int s = 0; s < 2; ++s) w1f[s] = mkWfrag(fold + F_W1, 16 * w + (lane & 15), 32 * s, lane);
#pragma unroll
  for (int r = 0; r < 4; ++r) bias2[r] = fold[F_B1 + 16 * w + 4 * (lane >> 4) + r];
#pragma unroll
  for (int ot = 0; ot < 2; ++ot) {
#pragma unroll
    for (int s = 0; s < 2; ++s)
      w2f[ot][s] = mkWfrag(fold + F_W2, 16 * (2 * w + ot) + (lane & 15), 32 * s, lane);
#pragma unroll
    for (int r = 0; r < 4; ++r) bias3[ot][r] = fold[F_B2 + 16 * (2 * w + ot) + 4 * (lane >> 4) + r];
  }
  for (int rep = 0; rep < 8; ++rep) {
    int g = blockIdx.x + rep * 2048;
    int b = g >> 10, s = g & 1023;
    __syncthreads();
    for (int i = tid; i < 384; i += 256) x1s[i] = x1[(size_t)g * 384 + i];
    __syncthreads();
    x2_to_pc(x1s, wf0s, bf0s, x2p, tid);
    __syncthreads();
#pragma unroll
    for (int t = 0; t < 4; ++t) {
      f4v acc; acc[0] = bias2[0]; acc[1] = bias2[1]; acc[2] = bias2[2]; acc[3] = bias2[3];
      acc = mm(w1f[0], ldB_pc(x2p, t, lane, 0), acc);
      acc = mm(w1f[1], ldB_pc(x2p, t, lane, 32), acc);
      s4v v;
#pragma unroll
      for (int r = 0; r < 4; ++r) v[r] = f2bf(fmaxf(acc[r], 0.f));
      int p = 16 * t + (lane & 15);
      int cb = 16 * w + 4 * (lane >> 4);
      *(s4v*)&x3p[(p << 6) + (((cb >> 2) ^ SW(p)) << 2)] = v;
    }
    __syncthreads();
    float vmax[2][4];
#pragma unroll
    for (int t = 0; t < 4; ++t) {
      s8v b0f = ldB_pc(x3p, t, lane, 0);
      s8v b1f = ldB_pc(x3p, t, lane, 32);
#pragma unroll
      for (int ot = 0; ot < 2; ++ot) {
        f4v acc; acc[0] = bias3[ot][0]; acc[1] = bias3[ot][1]; acc[2] = bias3[ot][2]; acc[3] = bias3[ot][3];
        acc = mm(w2f[ot][0], b0f, acc);
        acc = mm(w2f[ot][1], b1f, acc);
#pragma unroll
        for (int r = 0; r < 4; ++r)
          vmax[ot][r] = (t == 0) ? acc[r] : fmaxf(vmax[ot][r], acc[r]);
      }
    }
#pragma unroll
    for (int ot = 0; ot < 2; ++ot)
#pragma unroll
      for (int r = 0; r < 4; ++r) {
        float m = rowmax16(vmax[ot][r]);
        if ((lane & 15) == 15) {
          int o = 16 * (2 * w + ot) + 4 * (lane >> 4) + r;
          out[((size_t)b * 128 + o) * NS + s] = fmaxf(m, 0.f);
        }
      }
  }
}

extern "C" void kernel_launch(void* const* d_in, const int* in_sizes, int n_in,
                              void* d_out, int out_size, void* d_ws, size_t ws_size,
                              hipStream_t stream) {
  (void)in_sizes; (void)n_in; (void)out_size; (void)ws_size;
  const float* feature = (const float*)d_in[0];
  const float* coord = (const float*)d_in[1];
  const float* W0 = (const float*)d_in[2];  const float* b0 = (const float*)d_in[3];
  const float* g0 = (const float*)d_in[4];  const float* be0 = (const float*)d_in[5];
  const float* W1 = (const float*)d_in[6];  const float* b1 = (const float*)d_in[7];
  const float* g1 = (const float*)d_in[8];  const float* be1 = (const float*)d_in[9];
  const float* W2 = (const float*)d_in[10]; const float* b2 = (const float*)d_in[11];
  const float* g2 = (const float*)d_in[12]; const float* be2 = (const float*)d_in[13];
  float* out = (float*)d_out;
  float* ws = (float*)d_ws;
  float* newxyz = ws + OFF_NEWXYZ;
  float* x1 = ws + OFF_X1;
  float* stats = ws + OFF_STATS;
  float* fold = ws + OFF_FOLD;
  hipMemsetAsync(stats, 0, (size_t)NCOPY * ST_LEN * sizeof(float), stream);
  hipLaunchKernelGGL(k_fps, dim3(NB), dim3(512), 0, stream, coord, newxyz, out + OUTC_OFF);
  hipLaunchKernelGGL(k_group, dim3(4096), dim3(256), 0, stream, coord, feature, newxyz, x1);
  hipLaunchKernelGGL(k_stats1, dim3(256), dim3(256), 0, stream, x1, stats);
  hipLaunchKernelGGL(k_fold1, dim3(1), dim3(256), 0, stream, W0, b0, g0, be0, stats, fold);
  hipLaunchKernelGGL(k_pass2, dim3(512), dim3(256), 0, stream, x1, fold, stats);
  hipLaunchKernelGGL(k_fold2, dim3(1), dim3(256), 0, stream, W1, b1, g1, be1, stats, fold);
  hipLaunchKernelGGL(k_pass3, dim3(512), dim3(256), 0, stream, x1, fold, stats);
  hipLaunchKernelGGL(k_fold3, dim3(1), dim3(256), 0, stream, W2, b2, g2, be2, stats, fold);
  hipLaunchKernelGGL(k_final, dim3(2048), dim3(256), 0, stream, x1, fold, out);
}

// Round 12
// 1081.875 us; speedup vs baseline: 1.0480x; 1.0480x over previous
//
#include <hip/hip_runtime.h>
#include <hip/hip_bf16.h>
#include <math.h>

#define NB 16
#define NPT 4096
#define NS 1024
#define NK 64
#define CNTF 1048576.0f
#define R2C 0.04f
#define BNEPS 1e-5f

// ws float offsets
#define OFF_NEWXYZ 0
#define OFF_X1     49152
#define OFF_STATS  6340608           // 32 copies x ST_LEN
#define NCOPY 32
#define ST_LEN 8352
#define OFF_FOLD   6607872           // 6340608 + 32*8352
#define ST_M1 0
#define ST_G1 6
#define ST_M2 27
#define ST_G2 91
#define ST_M3 4187
#define ST_G3 4251
#define F_W0 0
#define F_B0 384
#define F_W1 448
#define F_B1 4544
#define F_W2 4608
#define F_B2 12800
#define OUTC_OFF 2097152

typedef __attribute__((ext_vector_type(8))) short s8v;
typedef __attribute__((ext_vector_type(4))) short s4v;
typedef __attribute__((ext_vector_type(4))) float f4v;

__device__ __forceinline__ float bf2f(short s) {
  return __uint_as_float(((unsigned)(unsigned short)s) << 16);
}
__device__ __forceinline__ short f2bf(float f) {
  unsigned u = __float_as_uint(f);
  return (short)((u + 0x7fff + ((u >> 16) & 1)) >> 16);
}
__device__ __forceinline__ int SW(int p) {
  return (((p) & 7) << 1) | (((p) >> 3) & 1);
}
__device__ __forceinline__ f4v mm(s8v a, s8v b, f4v c) {
  return __builtin_amdgcn_mfma_f32_16x16x32_bf16(a, b, c, 0, 0, 0);
}
__device__ __forceinline__ s8v ldB_pc(const short* x, int t, int l, int kb) {
  int p = t * 16 + (l & 15);
  int c0 = kb + 4 * (l >> 4);
  int base = p << 6;
  s4v a = *(const s4v*)&x[base + ((((c0) >> 2) ^ SW(p)) << 2)];
  s4v b = *(const s4v*)&x[base + ((((c0 + 16) >> 2) ^ SW(p)) << 2)];
  s8v r; r[0]=a[0]; r[1]=a[1]; r[2]=a[2]; r[3]=a[3]; r[4]=b[0]; r[5]=b[1]; r[6]=b[2]; r[7]=b[3];
  return r;
}
__device__ __forceinline__ s8v ldG_cp(const short* x, int ct, int l, int pb) {
  int c = ct * 16 + (l & 15);
  int p0 = pb + 4 * (l >> 4);
  int base = c << 6;
  s4v a = *(const s4v*)&x[base + ((((p0) >> 2) ^ SW(c)) << 2)];
  s4v b = *(const s4v*)&x[base + ((((p0 + 16) >> 2) ^ SW(c)) << 2)];
  s8v r; r[0]=a[0]; r[1]=a[1]; r[2]=a[2]; r[3]=a[3]; r[4]=b[0]; r[5]=b[1]; r[6]=b[2]; r[7]=b[3];
  return r;
}
__device__ __forceinline__ s8v mkWfrag(const float* W, int row, int kb, int l) {
  int c0 = kb + 4 * (l >> 4);
  s8v f;
#pragma unroll
  for (int j = 0; j < 4; ++j) f[j] = f2bf(W[row * 64 + c0 + j]);
#pragma unroll
  for (int j = 0; j < 4; ++j) f[4 + j] = f2bf(W[row * 64 + c0 + 16 + j]);
  return f;
}
__device__ __forceinline__ s8v onesfrag() {
  s8v f;
#pragma unroll
  for (int j = 0; j < 8; ++j) f[j] = (short)0x3F80;
  return f;
}
__device__ __forceinline__ float rowmax16(float x) {
#define DPPMAX(ctrl)                                                          \
  x = fmaxf(x, __int_as_float(__builtin_amdgcn_update_dpp(                    \
             0, __float_as_int(x), ctrl, 0xf, 0xf, true)))
  DPPMAX(0x111); DPPMAX(0x112); DPPMAX(0x114); DPPMAX(0x118);
#undef DPPMAX
  return x;
}

// ---------------- FPS: exact round-6 structure (measured best: 651 us) -------
// 512 threads, 8 pts/lane in registers. Per iteration: update -> DPP row max
// + 4 readlane -> ballot+ctz first-occurrence -> lead writes packed u64 key
// -> ONE barrier -> 8-key scan -> centroid broadcast read from sxyz[fi].
__launch_bounds__(512)
__global__ void k_fps(const float* __restrict__ coord, float* __restrict__ newxyz,
                      float* __restrict__ out_coord) {
#pragma clang fp contract(off)
  __shared__ float4 sxyz[NPT];
  __shared__ int sel[NS];
  __shared__ unsigned long long skey[2][8];
  int b = blockIdx.x;
  int tid = threadIdx.x;
  int w = tid >> 6, lane = tid & 63;
  const float* cb = coord + (size_t)b * 3 * NPT;
  for (int i = tid; i < NPT; i += 512)
    sxyz[i] = make_float4(cb[i], cb[NPT + i], cb[2 * NPT + i], 0.f);
  __syncthreads();
  float px[8], py[8], pz[8], dd[8];
  int base = tid * 8;
#pragma unroll
  for (int j = 0; j < 8; ++j) {
    float4 p = sxyz[base + j];
    px[j] = p.x; py[j] = p.y; pz[j] = p.z; dd[j] = 1e10f;
  }
  if (tid == 0) sel[0] = 0;
  float4 c0 = sxyz[0];
  float cx = c0.x, cy = c0.y, cz = c0.z;
  for (int it = 1; it < NS; ++it) {
    float nd[8];
#pragma unroll
    for (int j = 0; j < 8; ++j) {
      float dx = px[j] - cx, dy = py[j] - cy, dz = pz[j] - cz;
      float d = dx * dx; d = d + dy * dy; d = d + dz * dz;
      float v = fminf(dd[j], d); dd[j] = v; nd[j] = v;
    }
    float bv = nd[0];
#pragma unroll
    for (int j = 1; j < 8; ++j) bv = fmaxf(bv, nd[j]);
    int bj = 7;
#pragma unroll
    for (int j = 6; j >= 0; --j) bj = (nd[j] == bv) ? j : bj;
    int bi = base + bj;
    float rm = rowmax16(bv);
    float r0 = __int_as_float(__builtin_amdgcn_readlane(__float_as_int(rm), 15));
    float r1 = __int_as_float(__builtin_amdgcn_readlane(__float_as_int(rm), 31));
    float r2 = __int_as_float(__builtin_amdgcn_readlane(__float_as_int(rm), 47));
    float r3 = __int_as_float(__builtin_amdgcn_readlane(__float_as_int(rm), 63));
    float wmax = fmaxf(fmaxf(r0, r1), fmaxf(r2, r3));
    unsigned long long mm2 = __ballot(bv == wmax);
    int lead = (int)__builtin_ctzll(mm2);
    int wbi = __builtin_amdgcn_readlane(bi, lead);
    int par = it & 1;
    if (lane == 0)
      skey[par][w] = ((unsigned long long)__float_as_uint(wmax) << 32) |
                     (unsigned)(4095 - wbi);
    __syncthreads();
    unsigned long long g = skey[par][0];
#pragma unroll
    for (int q = 1; q < 8; ++q) {
      unsigned long long o = skey[par][q];
      g = g > o ? g : o;
    }
    int fi = 4095 - (int)(g & 0xffffffffu);
    if (tid == 0) sel[it] = fi;
    float4 cc = sxyz[fi];
    cx = cc.x; cy = cc.y; cz = cc.z;
  }
  __syncthreads();
  for (int s = tid; s < NS; s += 512) {
    int i = sel[s];
    float4 p = sxyz[i];
    newxyz[((size_t)b * NS + s) * 3 + 0] = p.x;
    newxyz[((size_t)b * NS + s) * 3 + 1] = p.y;
    newxyz[((size_t)b * NS + s) * 3 + 2] = p.z;
    out_coord[((size_t)b * 3 + 0) * NS + s] = p.x;
    out_coord[((size_t)b * 3 + 1) * NS + s] = p.y;
    out_coord[((size_t)b * 3 + 2) * NS + s] = p.z;
  }
}

// ------ Ball query + grouping (prefetch) + FUSED x1 stats (mean6+gram21) -----
__launch_bounds__(256)
__global__ void k_group(const float* __restrict__ coord, const float* __restrict__ feat,
                        const float* __restrict__ newxyz, float* __restrict__ x1,
                        float* __restrict__ stats) {
#pragma clang fp contract(off)
  __shared__ float st[4][6][64];
  __shared__ float sred[4][27];
  int tid = threadIdx.x;
  int w = tid >> 6, lane = tid & 63;
  int g = blockIdx.x * 4 + w;
  int b = g >> 10;
  const float* cb = coord + (size_t)b * 3 * NPT;
  const float* fb = feat + (size_t)b * 3 * NPT;
  float cx = newxyz[(size_t)g * 3 + 0], cy = newxyz[(size_t)g * 3 + 1], cz = newxyz[(size_t)g * 3 + 2];
  int cnt = 0;
  float x = cb[lane], y = cb[NPT + lane], z = cb[2 * NPT + lane];
  for (int ch = 0; ch < NPT / 64 && cnt < 64; ++ch) {
    float xn = 0.f, yn = 0.f, zn = 0.f;
    if (ch + 1 < NPT / 64) {
      int pn = (ch + 1) * 64 + lane;
      xn = cb[pn]; yn = cb[NPT + pn]; zn = cb[2 * NPT + pn];
    }
    int p = ch * 64 + lane;
    float dx = x - cx, dy = y - cy, dz = z - cz;
    float d = dx * dx; d = d + dy * dy; d = d + dz * dz;
    bool in = (d <= R2C);
    unsigned long long m = __ballot(in);
    int rank = __popcll(m & ((1ull << lane) - 1ull));
    int slot = cnt + rank;
    if (in && slot < 64) {
      st[w][0][slot] = dx; st[w][1][slot] = dy; st[w][2][slot] = dz;
      st[w][3][slot] = fb[p]; st[w][4][slot] = fb[NPT + p]; st[w][5][slot] = fb[2 * NPT + p];
    }
    cnt += (int)__popcll(m);
    x = xn; y = yn; z = zn;
  }
  __syncthreads();
  cnt = min(cnt, 64);
  if (lane >= cnt) {
#pragma unroll
    for (int c = 0; c < 6; ++c) st[w][c][lane] = st[w][c][0];
  }
  float* dst = x1 + (size_t)g * 384;
  float v[6];
#pragma unroll
  for (int c = 0; c < 6; ++c) { v[c] = st[w][c][lane]; dst[c * 64 + lane] = v[c]; }
  // fused stats: per-lane column contribution -> wave reduce -> block reduce
  float acc[27];
  {
    int q = 0;
#pragma unroll
    for (int c = 0; c < 6; ++c) acc[q++] = v[c];
#pragma unroll
    for (int c = 0; c < 6; ++c)
#pragma unroll
      for (int c2 = c; c2 < 6; ++c2) acc[q++] = v[c] * v[c2];
  }
#pragma unroll
  for (int q = 0; q < 27; ++q) {
    float t = acc[q];
    for (int o = 1; o < 64; o <<= 1) t += __shfl_xor(t, o);
    if (lane == 0) sred[w][q] = t;
  }
  __syncthreads();
  if (tid < 27) {
    float s = sred[0][tid] + sred[1][tid] + sred[2][tid] + sred[3][tid];
    float* stc = stats + (size_t)(blockIdx.x & (NCOPY - 1)) * ST_LEN;
    atomicAdd(&stc[tid], s);   // ST_M1=0..5 then ST_G1=6..26, contiguous
  }
}

// ---------------- fold kernels (sum 32 copies, then fold) --------------------
__launch_bounds__(256)
__global__ void k_fold1(const float* __restrict__ W0, const float* __restrict__ b0,
                        const float* __restrict__ g0, const float* __restrict__ be0,
                        const float* __restrict__ stats, float* __restrict__ fold) {
  __shared__ float sMG[27];
  int tid = threadIdx.x;
  if (tid < 27) {
    float s = 0.f;
    for (int cp = 0; cp < NCOPY; ++cp) s += stats[(size_t)cp * ST_LEN + tid];
    sMG[tid] = s;
  }
  __syncthreads();
  int o = tid;
  if (o >= 64) return;
  float G[6][6], mu[6];
  {
    int q = 0;
    for (int c = 0; c < 6; ++c)
      for (int c2 = c; c2 < 6; ++c2) { float v = sMG[ST_G1 + q] / CNTF; G[c][c2] = v; G[c2][c] = v; q++; }
    for (int c = 0; c < 6; ++c) mu[c] = sMG[ST_M1 + c] / CNTF;
  }
  float w[6];
  for (int c = 0; c < 6; ++c) w[c] = W0[o * 6 + c];
  float bb = b0[o];
  float s1 = 0.f, ey2 = 0.f;
  for (int c = 0; c < 6; ++c) {
    s1 += w[c] * mu[c];
    for (int c2 = 0; c2 < 6; ++c2) ey2 += w[c] * w[c2] * G[c][c2];
  }
  float muy = s1 + bb;
  ey2 = ey2 + 2.f * bb * s1 + bb * bb;
  float var = ey2 - muy * muy;
  float sc = g0[o] / sqrtf(var + BNEPS);
  for (int c = 0; c < 6; ++c) fold[F_W0 + o * 6 + c] = w[c] * sc;
  fold[F_B0 + o] = (bb - muy) * sc + be0[o];
}

__launch_bounds__(256)
__global__ void k_fold2(const float* __restrict__ W1, const float* __restrict__ b1,
                        const float* __restrict__ g1, const float* __restrict__ be1,
                        const float* __restrict__ stats, float* __restrict__ fold) {
  __shared__ float sG[4096];
  __shared__ float sM[64];
  int tid = threadIdx.x;
  for (int i = tid; i < 4096; i += 256) {
    float s = 0.f;
    for (int cp = 0; cp < NCOPY; ++cp) s += stats[(size_t)cp * ST_LEN + ST_G2 + i];
    sG[i] = s;
  }
  if (tid < 64) {
    float s = 0.f;
    for (int cp = 0; cp < NCOPY; ++cp) s += stats[(size_t)cp * ST_LEN + ST_M2 + tid];
    sM[tid] = s;
  }
  __syncthreads();
  int o = tid;
  if (o >= 64) return;
  float s1 = 0.f, ey2 = 0.f;
  for (int c = 0; c < 64; ++c) {
    float w = W1[o * 64 + c];
    s1 += w * sM[c];
    float t = 0.f;
    for (int c2 = 0; c2 < 64; ++c2) t += W1[o * 64 + c2] * sG[c * 64 + c2];
    ey2 += w * t;
  }
  s1 /= CNTF; ey2 /= CNTF;
  float bb = b1[o];
  float muy = s1 + bb;
  ey2 = ey2 + 2.f * bb * s1 + bb * bb;
  float var = ey2 - muy * muy;
  float sc = g1[o] / sqrtf(var + BNEPS);
  for (int c = 0; c < 64; ++c) fold[F_W1 + o * 64 + c] = W1[o * 64 + c] * sc;
  fold[F_B1 + o] = (bb - muy) * sc + be1[o];
}

__launch_bounds__(256)
__global__ void k_fold3(const float* __restrict__ W2, const float* __restrict__ b2,
                        const float* __restrict__ g2, const float* __restrict__ be2,
                        const float* __restrict__ stats, float* __restrict__ fold) {
  __shared__ float sG[4096];
  __shared__ float sM[64];
  int tid = threadIdx.x;
  for (int i = tid; i < 4096; i += 256) {
    float s = 0.f;
    for (int cp = 0; cp < NCOPY; ++cp) s += stats[(size_t)cp * ST_LEN + ST_G3 + i];
    sG[i] = s;
  }
  if (tid < 64) {
    float s = 0.f;
    for (int cp = 0; cp < NCOPY; ++cp) s += stats[(size_t)cp * ST_LEN + ST_M3 + tid];
    sM[tid] = s;
  }
  __syncthreads();
  int o = tid;
  if (o >= 128) return;
  float s1 = 0.f, ey2 = 0.f;
  for (int c = 0; c < 64; ++c) {
    float w = W2[o * 64 + c];
    s1 += w * sM[c];
    float t = 0.f;
    for (int c2 = 0; c2 < 64; ++c2) t += W2[o * 64 + c2] * sG[c * 64 + c2];
    ey2 += w * t;
  }
  s1 /= CNTF; ey2 /= CNTF;
  float bb = b2[o];
  float muy = s1 + bb;
  ey2 = ey2 + 2.f * bb * s1 + bb * bb;
  float var = ey2 - muy * muy;
  float sc = g2[o] / sqrtf(var + BNEPS);
  for (int c = 0; c < 64; ++c) fold[F_W2 + o * 64 + c] = W2[o * 64 + c] * sc;
  fold[F_B2 + o] = (bb - muy) * sc + be2[o];
}

// conv1 (f32) -> x2 bf16 into [p][c] layout (swizzled)
__device__ __forceinline__ void x2_to_pc(const float* x1s, const float* wf0, const float* bf0,
                                         short* x2p, int tid) {
  int p = tid & 63, r = tid >> 6;
  float xin[6];
#pragma unroll
  for (int c = 0; c < 6; ++c) xin[c] = x1s[c * 64 + p];
#pragma unroll
  for (int m4 = 0; m4 < 4; ++m4) {
    s4v v;
#pragma unroll
    for (int u = 0; u < 4; ++u) {
      int o = r * 16 + m4 * 4 + u;
      float a = bf0[o];
#pragma unroll
      for (int c = 0; c < 6; ++c) a += wf0[o * 6 + c] * xin[c];
      v[u] = f2bf(fmaxf(a, 0.f));
    }
    int cb = r * 16 + m4 * 4;
    *(s4v*)&x2p[(p << 6) + (((cb >> 2) ^ SW(p)) << 2)] = v;
  }
}
// conv1 (f32) -> x2 bf16 into [c][p] layout (swizzled)
__device__ __forceinline__ void x2_to_cp(const float* x1s, const float* wf0, const float* bf0,
                                         short* x2c, int tid) {
  int p = tid & 63, r = tid >> 6;
  float xin[6];
#pragma unroll
  for (int c = 0; c < 6; ++c) xin[c] = x1s[c * 64 + p];
#pragma unroll
  for (int i = 0; i < 16; ++i) {
    int o = r * 16 + i;
    float a = bf0[o];
#pragma unroll
    for (int c = 0; c < 6; ++c) a += wf0[o * 6 + c] * xin[c];
    x2c[(o << 6) + (((p >> 2) ^ SW(o)) << 2) + (p & 3)] = f2bf(fmaxf(a, 0.f));
  }
}

// ---------------- pass2: x2 stats via MFMA gram + ones-mean ------------------
__launch_bounds__(256)
__global__ void k_pass2(const float* __restrict__ x1, const float* __restrict__ fold,
                        float* __restrict__ stats) {
  __shared__ float x1s[384];
  __shared__ float wf0s[384];
  __shared__ float bf0s[64];
  __shared__ short x2c[4096];
  int tid = threadIdx.x;
  int lane = tid & 63, w = tid >> 6;
  float* st = stats + (size_t)(blockIdx.x & (NCOPY - 1)) * ST_LEN;
  for (int i = tid; i < 384; i += 256) wf0s[i] = fold[F_W0 + i];
  if (tid < 64) bf0s[tid] = fold[F_B0 + tid];
  s8v ones = onesfrag();
  f4v gacc[4] = {};
  f4v maccv = {};
  for (int rep = 0; rep < 32; ++rep) {
    int g = blockIdx.x + rep * 512;
    __syncthreads();
    for (int i = tid; i < 384; i += 256) x1s[i] = x1[(size_t)g * 384 + i];
    __syncthreads();
    x2_to_cp(x1s, wf0s, bf0s, x2c, tid);
    __syncthreads();
#pragma unroll
    for (int pb = 0; pb < 64; pb += 32) {
      s8v a = ldG_cp(x2c, w, lane, pb);
      maccv = mm(a, ones, maccv);
#pragma unroll
      for (int ct = 0; ct < 4; ++ct)
        gacc[ct] = mm(a, ldG_cp(x2c, ct, lane, pb), gacc[ct]);
    }
  }
#pragma unroll
  for (int ct = 0; ct < 4; ++ct)
#pragma unroll
    for (int r = 0; r < 4; ++r) {
      int row = 16 * w + 4 * (lane >> 4) + r;
      int col = 16 * ct + (lane & 15);
      atomicAdd(&st[ST_G2 + row * 64 + col], gacc[ct][r]);
    }
  if ((lane & 15) == 0)
#pragma unroll
    for (int r = 0; r < 4; ++r)
      atomicAdd(&st[ST_M2 + 16 * w + 4 * (lane >> 4) + r], maccv[r]);
}

// ---------------- pass3: x3 stats via MFMA conv2 + gram + ones-mean ----------
__launch_bounds__(256)
__global__ void k_pass3(const float* __restrict__ x1, const float* __restrict__ fold,
                        float* __restrict__ stats) {
  __shared__ float x1s[384];
  __shared__ float wf0s[384];
  __shared__ float bf0s[64];
  __shared__ short x2p[4096];
  __shared__ short x3c[4096];
  int tid = threadIdx.x;
  int lane = tid & 63, w = tid >> 6;
  float* st = stats + (size_t)(blockIdx.x & (NCOPY - 1)) * ST_LEN;
  for (int i = tid; i < 384; i += 256) wf0s[i] = fold[F_W0 + i];
  if (tid < 64) bf0s[tid] = fold[F_B0 + tid];
  s8v w1f[2];
  float bias2[4];
#pragma unroll
  for (int s = 0; s < 2; ++s) w1f[s] = mkWfrag(fold + F_W1, 16 * w + (lane & 15), 32 * s, lane);
#pragma unroll
  for (int r = 0; r < 4; ++r) bias2[r] = fold[F_B1 + 16 * w + 4 * (lane >> 4) + r];
  s8v ones = onesfrag();
  f4v gacc[4] = {};
  f4v maccv = {};
  for (int rep = 0; rep < 32; ++rep) {
    int g = blockIdx.x + rep * 512;
    __syncthreads();
    for (int i = tid; i < 384; i += 256) x1s[i] = x1[(size_t)g * 384 + i];
    __syncthreads();
    x2_to_pc(x1s, wf0s, bf0s, x2p, tid);
    __syncthreads();
#pragma unroll
    for (int t = 0; t < 4; ++t) {
      f4v acc; acc[0] = bias2[0]; acc[1] = bias2[1]; acc[2] = bias2[2]; acc[3] = bias2[3];
      acc = mm(w1f[0], ldB_pc(x2p, t, lane, 0), acc);
      acc = mm(w1f[1], ldB_pc(x2p, t, lane, 32), acc);
      int p = 16 * t + (lane & 15);
#pragma unroll
      for (int r = 0; r < 4; ++r) {
        int c = 16 * w + 4 * (lane >> 4) + r;
        x3c[(c << 6) + (((p >> 2) ^ SW(c)) << 2) + (p & 3)] = f2bf(fmaxf(acc[r], 0.f));
      }
    }
    __syncthreads();
#pragma unroll
    for (int pb = 0; pb < 64; pb += 32) {
      s8v a = ldG_cp(x3c, w, lane, pb);
      maccv = mm(a, ones, maccv);
#pragma unroll
      for (int ct = 0; ct < 4; ++ct)
        gacc[ct] = mm(a, ldG_cp(x3c, ct, lane, pb), gacc[ct]);
    }
  }
#pragma unroll
  for (int ct = 0; ct < 4; ++ct)
#pragma unroll
    for (int r = 0; r < 4; ++r) {
      int row = 16 * w + 4 * (lane >> 4) + r;
      int col = 16 * ct + (lane & 15);
      atomicAdd(&st[ST_G3 + row * 64 + col], gacc[ct][r]);
    }
  if ((lane & 15) == 0)
#pragma unroll
    for (int r = 0; r < 4; ++r)
      atomicAdd(&st[ST_M3 + 16 * w + 4 * (lane >> 4) + r], maccv[r]);
}

// ---------------- final: conv2+conv3 MFMA + k-max ----------------------------
__launch_bounds__(256)
__global__ void k_final(const float* __restrict__ x1, const float* __restrict__ fold,
                        float* __restrict__ out) {
  __shared__ float x1s[384];
  __shared__ float wf0s[384];
  __shared__ float bf0s[64];
  __shared__ short x2p[4096];
  __shared__ short x3p[4096];
  int tid = threadIdx.x;
  int lane = tid & 63, w = tid >> 6;
  for (int i = tid; i < 384; i += 256) wf0s[i] = fold[F_W0 + i];
  if (tid < 64) bf0s[tid] = fold[F_B0 + tid];
  s8v w1f[2], w2f[2][2];
  float bias2[4], bias3[2][4];
#pragma unroll
  for (int s = 0; s < 2; ++s) w1f[s] = mkWfrag(fold + F_W1, 16 * w + (lane & 15), 32 * s, lane);
#pragma unroll
  for (int r = 0; r < 4; ++r) bias2[r] = fold[F_B1 + 16 * w + 4 * (lane >> 4) + r];
#pragma unroll
  for (int ot = 0; ot < 2; ++ot) {
#pragma unroll
    for (int s = 0; s < 2; ++s)
      w2f[ot][s] = mkWfrag(fold + F_W2, 16 * (2 * w + ot) + (lane & 15), 32 * s, lane);
#pragma unroll
    for (int r = 0; r < 4; ++r) bias3[ot][r] = fold[F_B2 + 16 * (2 * w + ot) + 4 * (lane >> 4) + r];
  }
  for (int rep = 0; rep < 8; ++rep) {
    int g = blockIdx.x + rep * 2048;
    int b = g >> 10, s = g & 1023;
    __syncthreads();
    for (int i = tid; i < 384; i += 256) x1s[i] = x1[(size_t)g * 384 + i];
    __syncthreads();
    x2_to_pc(x1s, wf0s, bf0s, x2p, tid);
    __syncthreads();
#pragma unroll
    for (int t = 0; t < 4; ++t) {
      f4v acc; acc[0] = bias2[0]; acc[1] = bias2[1]; acc[2] = bias2[2]; acc[3] = bias2[3];
      acc = mm(w1f[0], ldB_pc(x2p, t, lane, 0), acc);
      acc = mm(w1f[1], ldB_pc(x2p, t, lane, 32), acc);
      s4v v;
#pragma unroll
      for (int r = 0; r < 4; ++r) v[r] = f2bf(fmaxf(acc[r], 0.f));
      int p = 16 * t + (lane & 15);
      int cb = 16 * w + 4 * (lane >> 4);
      *(s4v*)&x3p[(p << 6) + (((cb >> 2) ^ SW(p)) << 2)] = v;
    }
    __syncthreads();
    float vmax[2][4];
#pragma unroll
    for (int t = 0; t < 4; ++t) {
      s8v b0f = ldB_pc(x3p, t, lane, 0);
      s8v b1f = ldB_pc(x3p, t, lane, 32);
#pragma unroll
      for (int ot = 0; ot < 2; ++ot) {
        f4v acc; acc[0] = bias3[ot][0]; acc[1] = bias3[ot][1]; acc[2] = bias3[ot][2]; acc[3] = bias3[ot][3];
        acc = mm(w2f[ot][0], b0f, acc);
        acc = mm(w2f[ot][1], b1f, acc);
#pragma unroll
        for (int r = 0; r < 4; ++r)
          vmax[ot][r] = (t == 0) ? acc[r] : fmaxf(vmax[ot][r], acc[r]);
      }
    }
#pragma unroll
    for (int ot = 0; ot < 2; ++ot)
#pragma unroll
      for (int r = 0; r < 4; ++r) {
        float m = rowmax16(vmax[ot][r]);
        if ((lane & 15) == 15) {
          int o = 16 * (2 * w + ot) + 4 * (lane >> 4) + r;
          out[((size_t)b * 128 + o) * NS + s] = fmaxf(m, 0.f);
        }
      }
  }
}

extern "C" void kernel_launch(void* const* d_in, const int* in_sizes, int n_in,
                              void* d_out, int out_size, void* d_ws, size_t ws_size,
                              hipStream_t stream) {
  (void)in_sizes; (void)n_in; (void)out_size; (void)ws_size;
  const float* feature = (const float*)d_in[0];
  const float* coord = (const float*)d_in[1];
  const float* W0 = (const float*)d_in[2];  const float* b0 = (const float*)d_in[3];
  const float* g0 = (const float*)d_in[4];  const float* be0 = (const float*)d_in[5];
  const float* W1 = (const float*)d_in[6];  const float* b1 = (const float*)d_in[7];
  const float* g1 = (const float*)d_in[8];  const float* be1 = (const float*)d_in[9];
  const float* W2 = (const float*)d_in[10]; const float* b2 = (const float*)d_in[11];
  const float* g2 = (const float*)d_in[12]; const float* be2 = (const float*)d_in[13];
  float* out = (float*)d_out;
  float* ws = (float*)d_ws;
  float* newxyz = ws + OFF_NEWXYZ;
  float* x1 = ws + OFF_X1;
  float* stats = ws + OFF_STATS;
  float* fold = ws + OFF_FOLD;
  hipMemsetAsync(stats, 0, (size_t)NCOPY * ST_LEN * sizeof(float), stream);
  hipLaunchKernelGGL(k_fps, dim3(NB), dim3(512), 0, stream, coord, newxyz, out + OUTC_OFF);
  hipLaunchKernelGGL(k_group, dim3(4096), dim3(256), 0, stream, coord, feature, newxyz, x1, stats);
  hipLaunchKernelGGL(k_fold1, dim3(1), dim3(256), 0, stream, W0, b0, g0, be0, stats, fold);
  hipLaunchKernelGGL(k_pass2, dim3(512), dim3(256), 0, stream, x1, fold, stats);
  hipLaunchKernelGGL(k_fold2, dim3(1), dim3(256), 0, stream, W1, b1, g1, be1, stats, fold);
  hipLaunchKernelGGL(k_pass3, dim3(512), dim3(256), 0, stream, x1, fold, stats);
  hipLaunchKernelGGL(k_fold3, dim3(1), dim3(256), 0, stream, W2, b2, g2, be2, stats, fold);
  hipLaunchKernelGGL(k_final, dim3(2048), dim3(256), 0, stream, x1, fold, out);
}

// Round 13
// 1065.802 us; speedup vs baseline: 1.0638x; 1.0151x over previous
//
#include <hip/hip_runtime.h>
#include <hip/hip_bf16.h>
#include <math.h>

#define NB 16
#define NPT 4096
#define NS 1024
#define NK 64
#define CNTF 1048576.0f
#define R2C 0.04f
#define BNEPS 1e-5f

// ws float offsets
#define OFF_NEWXYZ 0
#define OFF_X1     49152
#define OFF_STATS  6340608           // 32 copies x ST_LEN
#define NCOPY 32
#define ST_LEN 8352
#define OFF_FOLD   6607872           // 6340608 + 32*8352
#define ST_M1 0
#define ST_G1 6
#define ST_M2 27
#define ST_G2 91
#define ST_M3 4187
#define ST_G3 4251
#define F_W0 0
#define F_B0 384
#define F_W1 448
#define F_B1 4544
#define F_W2 4608
#define F_B2 12800
#define OUTC_OFF 2097152

typedef __attribute__((ext_vector_type(8))) short s8v;
typedef __attribute__((ext_vector_type(4))) short s4v;
typedef __attribute__((ext_vector_type(4))) float f4v;

__device__ __forceinline__ float bf2f(short s) {
  return __uint_as_float(((unsigned)(unsigned short)s) << 16);
}
__device__ __forceinline__ short f2bf(float f) {
  unsigned u = __float_as_uint(f);
  return (short)((u + 0x7fff + ((u >> 16) & 1)) >> 16);
}
__device__ __forceinline__ int SW(int p) {
  return (((p) & 7) << 1) | (((p) >> 3) & 1);
}
__device__ __forceinline__ f4v mm(s8v a, s8v b, f4v c) {
  return __builtin_amdgcn_mfma_f32_16x16x32_bf16(a, b, c, 0, 0, 0);
}
__device__ __forceinline__ s8v ldB_pc(const short* x, int t, int l, int kb) {
  int p = t * 16 + (l & 15);
  int c0 = kb + 4 * (l >> 4);
  int base = p << 6;
  s4v a = *(const s4v*)&x[base + ((((c0) >> 2) ^ SW(p)) << 2)];
  s4v b = *(const s4v*)&x[base + ((((c0 + 16) >> 2) ^ SW(p)) << 2)];
  s8v r; r[0]=a[0]; r[1]=a[1]; r[2]=a[2]; r[3]=a[3]; r[4]=b[0]; r[5]=b[1]; r[6]=b[2]; r[7]=b[3];
  return r;
}
__device__ __forceinline__ s8v ldG_cp(const short* x, int ct, int l, int pb) {
  int c = ct * 16 + (l & 15);
  int p0 = pb + 4 * (l >> 4);
  int base = c << 6;
  s4v a = *(const s4v*)&x[base + ((((p0) >> 2) ^ SW(c)) << 2)];
  s4v b = *(const s4v*)&x[base + ((((p0 + 16) >> 2) ^ SW(c)) << 2)];
  s8v r; r[0]=a[0]; r[1]=a[1]; r[2]=a[2]; r[3]=a[3]; r[4]=b[0]; r[5]=b[1]; r[6]=b[2]; r[7]=b[3];
  return r;
}
__device__ __forceinline__ s8v mkWfrag(const float* W, int row, int kb, int l) {
  int c0 = kb + 4 * (l >> 4);
  s8v f;
#pragma unroll
  for (int j = 0; j < 4; ++j) f[j] = f2bf(W[row * 64 + c0 + j]);
#pragma unroll
  for (int j = 0; j < 4; ++j) f[4 + j] = f2bf(W[row * 64 + c0 + 16 + j]);
  return f;
}
__device__ __forceinline__ s8v onesfrag() {
  s8v f;
#pragma unroll
  for (int j = 0; j < 8; ++j) f[j] = (short)0x3F80;
  return f;
}
__device__ __forceinline__ float rowmax16(float x) {
#define DPPMAX(ctrl)                                                          \
  x = fmaxf(x, __int_as_float(__builtin_amdgcn_update_dpp(                    \
             0, __float_as_int(x), ctrl, 0xf, 0xf, true)))
  DPPMAX(0x111); DPPMAX(0x112); DPPMAX(0x114); DPPMAX(0x118);
#undef DPPMAX
  return x;
}

// ---------------- FPS: exact round-6 structure (measured best: 651 us) -------
__launch_bounds__(512)
__global__ void k_fps(const float* __restrict__ coord, float* __restrict__ newxyz,
                      float* __restrict__ out_coord) {
#pragma clang fp contract(off)
  __shared__ float4 sxyz[NPT];
  __shared__ int sel[NS];
  __shared__ unsigned long long skey[2][8];
  int b = blockIdx.x;
  int tid = threadIdx.x;
  int w = tid >> 6, lane = tid & 63;
  const float* cb = coord + (size_t)b * 3 * NPT;
  for (int i = tid; i < NPT; i += 512)
    sxyz[i] = make_float4(cb[i], cb[NPT + i], cb[2 * NPT + i], 0.f);
  __syncthreads();
  float px[8], py[8], pz[8], dd[8];
  int base = tid * 8;
#pragma unroll
  for (int j = 0; j < 8; ++j) {
    float4 p = sxyz[base + j];
    px[j] = p.x; py[j] = p.y; pz[j] = p.z; dd[j] = 1e10f;
  }
  if (tid == 0) sel[0] = 0;
  float4 c0 = sxyz[0];
  float cx = c0.x, cy = c0.y, cz = c0.z;
  for (int it = 1; it < NS; ++it) {
    float nd[8];
#pragma unroll
    for (int j = 0; j < 8; ++j) {
      float dx = px[j] - cx, dy = py[j] - cy, dz = pz[j] - cz;
      float d = dx * dx; d = d + dy * dy; d = d + dz * dz;
      float v = fminf(dd[j], d); dd[j] = v; nd[j] = v;
    }
    float bv = nd[0];
#pragma unroll
    for (int j = 1; j < 8; ++j) bv = fmaxf(bv, nd[j]);
    int bj = 7;
#pragma unroll
    for (int j = 6; j >= 0; --j) bj = (nd[j] == bv) ? j : bj;
    int bi = base + bj;
    float rm = rowmax16(bv);
    float r0 = __int_as_float(__builtin_amdgcn_readlane(__float_as_int(rm), 15));
    float r1 = __int_as_float(__builtin_amdgcn_readlane(__float_as_int(rm), 31));
    float r2 = __int_as_float(__builtin_amdgcn_readlane(__float_as_int(rm), 47));
    float r3 = __int_as_float(__builtin_amdgcn_readlane(__float_as_int(rm), 63));
    float wmax = fmaxf(fmaxf(r0, r1), fmaxf(r2, r3));
    unsigned long long mm2 = __ballot(bv == wmax);
    int lead = (int)__builtin_ctzll(mm2);
    int wbi = __builtin_amdgcn_readlane(bi, lead);
    int par = it & 1;
    if (lane == 0)
      skey[par][w] = ((unsigned long long)__float_as_uint(wmax) << 32) |
                     (unsigned)(4095 - wbi);
    __syncthreads();
    unsigned long long g = skey[par][0];
#pragma unroll
    for (int q = 1; q < 8; ++q) {
      unsigned long long o = skey[par][q];
      g = g > o ? g : o;
    }
    int fi = 4095 - (int)(g & 0xffffffffu);
    if (tid == 0) sel[it] = fi;
    float4 cc = sxyz[fi];
    cx = cc.x; cy = cc.y; cz = cc.z;
  }
  __syncthreads();
  for (int s = tid; s < NS; s += 512) {
    int i = sel[s];
    float4 p = sxyz[i];
    newxyz[((size_t)b * NS + s) * 3 + 0] = p.x;
    newxyz[((size_t)b * NS + s) * 3 + 1] = p.y;
    newxyz[((size_t)b * NS + s) * 3 + 2] = p.z;
    out_coord[((size_t)b * 3 + 0) * NS + s] = p.x;
    out_coord[((size_t)b * 3 + 1) * NS + s] = p.y;
    out_coord[((size_t)b * 3 + 2) * NS + s] = p.z;
  }
}

// ------ Ball query + grouping (4pt/lane float4 scan) + FUSED x1 stats --------
// 256 points per wave-iteration: lane handles points [ch*256+4*lane, +4) via
// coalesced float4 loads. Index order preserved: p = ch*256 + 4*lane + j is
// lexicographic in (lane, j), so rank = cnt + sum_j popc(ballot_j & below) +
// own-lane prefix. ~8 serial iterations instead of ~30.
__launch_bounds__(256)
__global__ void k_group(const float* __restrict__ coord, const float* __restrict__ feat,
                        const float* __restrict__ newxyz, float* __restrict__ x1,
                        float* __restrict__ stats) {
#pragma clang fp contract(off)
  __shared__ float st[4][6][64];
  __shared__ float sred[4][27];
  int tid = threadIdx.x;
  int w = tid >> 6, lane = tid & 63;
  int g = blockIdx.x * 4 + w;
  int b = g >> 10;
  const float* cb = coord + (size_t)b * 3 * NPT;
  const float* fb = feat + (size_t)b * 3 * NPT;
  float cx = newxyz[(size_t)g * 3 + 0], cy = newxyz[(size_t)g * 3 + 1], cz = newxyz[(size_t)g * 3 + 2];
  unsigned long long below = (1ull << lane) - 1ull;
  int cnt = 0;
  for (int ch = 0; ch < NPT / 256 && cnt < 64; ++ch) {
    int pb = ch * 256 + 4 * lane;
    float4 x4 = *(const float4*)&cb[pb];
    float4 y4 = *(const float4*)&cb[NPT + pb];
    float4 z4 = *(const float4*)&cb[2 * NPT + pb];
    float xs[4], ys[4], zs[4], dxs[4], dys[4], dzs[4];
    bool in[4];
    xs[0] = x4.x; xs[1] = x4.y; xs[2] = x4.z; xs[3] = x4.w;
    ys[0] = y4.x; ys[1] = y4.y; ys[2] = y4.z; ys[3] = y4.w;
    zs[0] = z4.x; zs[1] = z4.y; zs[2] = z4.z; zs[3] = z4.w;
#pragma unroll
    for (int j = 0; j < 4; ++j) {
      float dx = xs[j] - cx, dy = ys[j] - cy, dz = zs[j] - cz;
      float d = dx * dx; d = d + dy * dy; d = d + dz * dz;
      dxs[j] = dx; dys[j] = dy; dzs[j] = dz;
      in[j] = (d <= R2C);
    }
    unsigned long long bm[4];
#pragma unroll
    for (int j = 0; j < 4; ++j) bm[j] = __ballot(in[j]);
    int lanebase = cnt + (int)__popcll(bm[0] & below) + (int)__popcll(bm[1] & below) +
                   (int)__popcll(bm[2] & below) + (int)__popcll(bm[3] & below);
    int own = 0;
#pragma unroll
    for (int j = 0; j < 4; ++j) {
      int slot = lanebase + own;
      if (in[j] && slot < 64) {
        int p = pb + j;
        st[w][0][slot] = dxs[j]; st[w][1][slot] = dys[j]; st[w][2][slot] = dzs[j];
        st[w][3][slot] = fb[p]; st[w][4][slot] = fb[NPT + p]; st[w][5][slot] = fb[2 * NPT + p];
      }
      own += in[j] ? 1 : 0;
    }
    cnt += (int)__popcll(bm[0]) + (int)__popcll(bm[1]) +
           (int)__popcll(bm[2]) + (int)__popcll(bm[3]);
  }
  __syncthreads();
  cnt = min(cnt, 64);
  if (lane >= cnt) {
#pragma unroll
    for (int c = 0; c < 6; ++c) st[w][c][lane] = st[w][c][0];
  }
  float* dst = x1 + (size_t)g * 384;
  float v[6];
#pragma unroll
  for (int c = 0; c < 6; ++c) { v[c] = st[w][c][lane]; dst[c * 64 + lane] = v[c]; }
  // fused stats: per-lane column contribution -> wave reduce -> block reduce
  float acc[27];
  {
    int q = 0;
#pragma unroll
    for (int c = 0; c < 6; ++c) acc[q++] = v[c];
#pragma unroll
    for (int c = 0; c < 6; ++c)
#pragma unroll
      for (int c2 = c; c2 < 6; ++c2) acc[q++] = v[c] * v[c2];
  }
#pragma unroll
  for (int q = 0; q < 27; ++q) {
    float t = acc[q];
    for (int o = 1; o < 64; o <<= 1) t += __shfl_xor(t, o);
    if (lane == 0) sred[w][q] = t;
  }
  __syncthreads();
  if (tid < 27) {
    float s = sred[0][tid] + sred[1][tid] + sred[2][tid] + sred[3][tid];
    float* stc = stats + (size_t)(blockIdx.x & (NCOPY - 1)) * ST_LEN;
    atomicAdd(&stc[tid], s);   // ST_M1=0..5 then ST_G1=6..26, contiguous
  }
}

// ---------------- fold kernels (sum 32 copies, then fold) --------------------
__launch_bounds__(256)
__global__ void k_fold1(const float* __restrict__ W0, const float* __restrict__ b0,
                        const float* __restrict__ g0, const float* __restrict__ be0,
                        const float* __restrict__ stats, float* __restrict__ fold) {
  __shared__ float sMG[27];
  int tid = threadIdx.x;
  if (tid < 27) {
    float s = 0.f;
    for (int cp = 0; cp < NCOPY; ++cp) s += stats[(size_t)cp * ST_LEN + tid];
    sMG[tid] = s;
  }
  __syncthreads();
  int o = tid;
  if (o >= 64) return;
  float G[6][6], mu[6];
  {
    int q = 0;
    for (int c = 0; c < 6; ++c)
      for (int c2 = c; c2 < 6; ++c2) { float v = sMG[ST_G1 + q] / CNTF; G[c][c2] = v; G[c2][c] = v; q++; }
    for (int c = 0; c < 6; ++c) mu[c] = sMG[ST_M1 + c] / CNTF;
  }
  float w[6];
  for (int c = 0; c < 6; ++c) w[c] = W0[o * 6 + c];
  float bb = b0[o];
  float s1 = 0.f, ey2 = 0.f;
  for (int c = 0; c < 6; ++c) {
    s1 += w[c] * mu[c];
    for (int c2 = 0; c2 < 6; ++c2) ey2 += w[c] * w[c2] * G[c][c2];
  }
  float muy = s1 + bb;
  ey2 = ey2 + 2.f * bb * s1 + bb * bb;
  float var = ey2 - muy * muy;
  float sc = g0[o] / sqrtf(var + BNEPS);
  for (int c = 0; c < 6; ++c) fold[F_W0 + o * 6 + c] = w[c] * sc;
  fold[F_B0 + o] = (bb - muy) * sc + be0[o];
}

__launch_bounds__(256)
__global__ void k_fold2(const float* __restrict__ W1, const float* __restrict__ b1,
                        const float* __restrict__ g1, const float* __restrict__ be1,
                        const float* __restrict__ stats, float* __restrict__ fold) {
  __shared__ float sG[4096];
  __shared__ float sM[64];
  int tid = threadIdx.x;
  for (int i = tid; i < 4096; i += 256) {
    float s = 0.f;
    for (int cp = 0; cp < NCOPY; ++cp) s += stats[(size_t)cp * ST_LEN + ST_G2 + i];
    sG[i] = s;
  }
  if (tid < 64) {
    float s = 0.f;
    for (int cp = 0; cp < NCOPY; ++cp) s += stats[(size_t)cp * ST_LEN + ST_M2 + tid];
    sM[tid] = s;
  }
  __syncthreads();
  int o = tid;
  if (o >= 64) return;
  float s1 = 0.f, ey2 = 0.f;
  for (int c = 0; c < 64; ++c) {
    float w = W1[o * 64 + c];
    s1 += w * sM[c];
    float t = 0.f;
    for (int c2 = 0; c2 < 64; ++c2) t += W1[o * 64 + c2] * sG[c * 64 + c2];
    ey2 += w * t;
  }
  s1 /= CNTF; ey2 /= CNTF;
  float bb = b1[o];
  float muy = s1 + bb;
  ey2 = ey2 + 2.f * bb * s1 + bb * bb;
  float var = ey2 - muy * muy;
  float sc = g1[o] / sqrtf(var + BNEPS);
  for (int c = 0; c < 64; ++c) fold[F_W1 + o * 64 + c] = W1[o * 64 + c] * sc;
  fold[F_B1 + o] = (bb - muy) * sc + be1[o];
}

__launch_bounds__(256)
__global__ void k_fold3(const float* __restrict__ W2, const float* __restrict__ b2,
                        const float* __restrict__ g2, const float* __restrict__ be2,
                        const float* __restrict__ stats, float* __restrict__ fold) {
  __shared__ float sG[4096];
  __shared__ float sM[64];
  int tid = threadIdx.x;
  for (int i = tid; i < 4096; i += 256) {
    float s = 0.f;
    for (int cp = 0; cp < NCOPY; ++cp) s += stats[(size_t)cp * ST_LEN + ST_G3 + i];
    sG[i] = s;
  }
  if (tid < 64) {
    float s = 0.f;
    for (int cp = 0; cp < NCOPY; ++cp) s += stats[(size_t)cp * ST_LEN + ST_M3 + tid];
    sM[tid] = s;
  }
  __syncthreads();
  int o = tid;
  if (o >= 128) return;
  float s1 = 0.f, ey2 = 0.f;
  for (int c = 0; c < 64; ++c) {
    float w = W2[o * 64 + c];
    s1 += w * sM[c];
    float t = 0.f;
    for (int c2 = 0; c2 < 64; ++c2) t += W2[o * 64 + c2] * sG[c * 64 + c2];
    ey2 += w * t;
  }
  s1 /= CNTF; ey2 /= CNTF;
  float bb = b2[o];
  float muy = s1 + bb;
  ey2 = ey2 + 2.f * bb * s1 + bb * bb;
  float var = ey2 - muy * muy;
  float sc = g2[o] / sqrtf(var + BNEPS);
  for (int c = 0; c < 64; ++c) fold[F_W2 + o * 64 + c] = W2[o * 64 + c] * sc;
  fold[F_B2 + o] = (bb - muy) * sc + be2[o];
}

// conv1 (f32) -> x2 bf16 into [p][c] layout (swizzled)
__device__ __forceinline__ void x2_to_pc(const float* x1s, const float* wf0, const float* bf0,
                                         short* x2p, int tid) {
  int p = tid & 63, r = tid >> 6;
  float xin[6];
#pragma unroll
  for (int c = 0; c < 6; ++c) xin[c] = x1s[c * 64 + p];
#pragma unroll
  for (int m4 = 0; m4 < 4; ++m4) {
    s4v v;
#pragma unroll
    for (int u = 0; u < 4; ++u) {
      int o = r * 16 + m4 * 4 + u;
      float a = bf0[o];
#pragma unroll
      for (int c = 0; c < 6; ++c) a += wf0[o * 6 + c] * xin[c];
      v[u] = f2bf(fmaxf(a, 0.f));
    }
    int cb = r * 16 + m4 * 4;
    *(s4v*)&x2p[(p << 6) + (((cb >> 2) ^ SW(p)) << 2)] = v;
  }
}
// conv1 (f32) -> x2 bf16 into [c][p] layout (swizzled)
__device__ __forceinline__ void x2_to_cp(const float* x1s, const float* wf0, const float* bf0,
                                         short* x2c, int tid) {
  int p = tid & 63, r = tid >> 6;
  float xin[6];
#pragma unroll
  for (int c = 0; c < 6; ++c) xin[c] = x1s[c * 64 + p];
#pragma unroll
  for (int i = 0; i < 16; ++i) {
    int o = r * 16 + i;
    float a = bf0[o];
#pragma unroll
    for (int c = 0; c < 6; ++c) a += wf0[o * 6 + c] * xin[c];
    x2c[(o << 6) + (((p >> 2) ^ SW(o)) << 2) + (p & 3)] = f2bf(fmaxf(a, 0.f));
  }
}

// ---------------- pass2: x2 stats via MFMA gram + ones-mean ------------------
__launch_bounds__(256)
__global__ void k_pass2(const float* __restrict__ x1, const float* __restrict__ fold,
                        float* __restrict__ stats) {
  __shared__ float x1s[384];
  __shared__ float wf0s[384];
  __shared__ float bf0s[64];
  __shared__ short x2c[4096];
  int tid = threadIdx.x;
  int lane = tid & 63, w = tid >> 6;
  float* st = stats + (size_t)(blockIdx.x & (NCOPY - 1)) * ST_LEN;
  for (int i = tid; i < 384; i += 256) wf0s[i] = fold[F_W0 + i];
  if (tid < 64) bf0s[tid] = fold[F_B0 + tid];
  s8v ones = onesfrag();
  f4v gacc[4] = {};
  f4v maccv = {};
  for (int rep = 0; rep < 32; ++rep) {
    int g = blockIdx.x + rep * 512;
    __syncthreads();
    for (int i = tid; i < 384; i += 256) x1s[i] = x1[(size_t)g * 384 + i];
    __syncthreads();
    x2_to_cp(x1s, wf0s, bf0s, x2c, tid);
    __syncthreads();
#pragma unroll
    for (int pb = 0; pb < 64; pb += 32) {
      s8v a = ldG_cp(x2c, w, lane, pb);
      maccv = mm(a, ones, maccv);
#pragma unroll
      for (int ct = 0; ct < 4; ++ct)
        gacc[ct] = mm(a, ldG_cp(x2c, ct, lane, pb), gacc[ct]);
    }
  }
#pragma unroll
  for (int ct = 0; ct < 4; ++ct)
#pragma unroll
    for (int r = 0; r < 4; ++r) {
      int row = 16 * w + 4 * (lane >> 4) + r;
      int col = 16 * ct + (lane & 15);
      atomicAdd(&st[ST_G2 + row * 64 + col], gacc[ct][r]);
    }
  if ((lane & 15) == 0)
#pragma unroll
    for (int r = 0; r < 4; ++r)
      atomicAdd(&st[ST_M2 + 16 * w + 4 * (lane >> 4) + r], maccv[r]);
}

// ---------------- pass3: x3 stats via MFMA conv2 + gram + ones-mean ----------
__launch_bounds__(256)
__global__ void k_pass3(const float* __restrict__ x1, const float* __restrict__ fold,
                        float* __restrict__ stats) {
  __shared__ float x1s[384];
  __shared__ float wf0s[384];
  __shared__ float bf0s[64];
  __shared__ short x2p[4096];
  __shared__ short x3c[4096];
  int tid = threadIdx.x;
  int lane = tid & 63, w = tid >> 6;
  float* st = stats + (size_t)(blockIdx.x & (NCOPY - 1)) * ST_LEN;
  for (int i = tid; i < 384; i += 256) wf0s[i] = fold[F_W0 + i];
  if (tid < 64) bf0s[tid] = fold[F_B0 + tid];
  s8v w1f[2];
  float bias2[4];
#pragma unroll
  for (int s = 0; s < 2; ++s) w1f[s] = mkWfrag(fold + F_W1, 16 * w + (lane & 15), 32 * s, lane);
#pragma unroll
  for (int r = 0; r < 4; ++r) bias2[r] = fold[F_B1 + 16 * w + 4 * (lane >> 4) + r];
  s8v ones = onesfrag();
  f4v gacc[4] = {};
  f4v maccv = {};
  for (int rep = 0; rep < 32; ++rep) {
    int g = blockIdx.x + rep * 512;
    __syncthreads();
    for (int i = tid; i < 384; i += 256) x1s[i] = x1[(size_t)g * 384 + i];
    __syncthreads();
    x2_to_pc(x1s, wf0s, bf0s, x2p, tid);
    __syncthreads();
#pragma unroll
    for (int t = 0; t < 4; ++t) {
      f4v acc; acc[0] = bias2[0]; acc[1] = bias2[1]; acc[2] = bias2[2]; acc[3] = bias2[3];
      acc = mm(w1f[0], ldB_pc(x2p, t, lane, 0), acc);
      acc = mm(w1f[1], ldB_pc(x2p, t, lane, 32), acc);
      int p = 16 * t + (lane & 15);
#pragma unroll
      for (int r = 0; r < 4; ++r) {
        int c = 16 * w + 4 * (lane >> 4) + r;
        x3c[(c << 6) + (((p >> 2) ^ SW(c)) << 2) + (p & 3)] = f2bf(fmaxf(acc[r], 0.f));
      }
    }
    __syncthreads();
#pragma unroll
    for (int pb = 0; pb < 64; pb += 32) {
      s8v a = ldG_cp(x3c, w, lane, pb);
      maccv = mm(a, ones, maccv);
#pragma unroll
      for (int ct = 0; ct < 4; ++ct)
        gacc[ct] = mm(a, ldG_cp(x3c, ct, lane, pb), gacc[ct]);
    }
  }
#pragma unroll
  for (int ct = 0; ct < 4; ++ct)
#pragma unroll
    for (int r = 0; r < 4; ++r) {
      int row = 16 * w + 4 * (lane >> 4) + r;
      int col = 16 * ct + (lane & 15);
      atomicAdd(&st[ST_G3 + row * 64 + col], gacc[ct][r]);
    }
  if ((lane & 15) == 0)
#pragma unroll
    for (int r = 0; r < 4; ++r)
      atomicAdd(&st[ST_M3 + 16 * w + 4 * (lane >> 4) + r], maccv[r]);
}

// ---------------- final: conv2+conv3 MFMA + k-max ----------------------------
__launch_bounds__(256)
__global__ void k_final(const float* __restrict__ x1, const float* __restrict__ fold,
                        float* __restrict__ out) {
  __shared__ float x1s[384];
  __shared__ float wf0s[384];
  __shared__ float bf0s[64];
  __shared__ short x2p[4096];
  __shared__ short x3p[4096];
  int tid = threadIdx.x;
  int lane = tid & 63, w = tid >> 6;
  for (int i = tid; i < 384; i += 256) wf0s[i] = fold[F_W0 + i];
  if (tid < 64) bf0s[tid] = fold[F_B0 + tid];
  s8v w1f[2], w2f[2][2];
  float bias2[4], bias3[2][4];
#pragma unroll
  for (int s = 0; s < 2; ++s) w1f[s] = mkWfrag(fold + F_W1, 16 * w + (lane & 15), 32 * s, lane);
#pragma unroll
  for (int r = 0; r < 4; ++r) bias2[r] = fold[F_B1 + 16 * w + 4 * (lane >> 4) + r];
#pragma unroll
  for (int ot = 0; ot < 2; ++ot) {
#pragma unroll
    for (int s = 0; s < 2; ++s)
      w2f[ot][s] = mkWfrag(fold + F_W2, 16 * (2 * w + ot) + (lane & 15), 32 * s, lane);
#pragma unroll
    for (int r = 0; r < 4; ++r) bias3[ot][r] = fold[F_B2 + 16 * (2 * w + ot) + 4 * (lane >> 4) + r];
  }
  for (int rep = 0; rep < 8; ++rep) {
    int g = blockIdx.x + rep * 2048;
    int b = g >> 10, s = g & 1023;
    __syncthreads();
    for (int i = tid; i < 384; i += 256) x1s[i] = x1[(size_t)g * 384 + i];
    __syncthreads();
    x2_to_pc(x1s, wf0s, bf0s, x2p, tid);
    __syncthreads();
#pragma unroll
    for (int t = 0; t < 4; ++t) {
      f4v acc; acc[0] = bias2[0]; acc[1] = bias2[1]; acc[2] = bias2[2]; acc[3] = bias2[3];
      acc = mm(w1f[0], ldB_pc(x2p, t, lane, 0), acc);
      acc = mm(w1f[1], ldB_pc(x2p, t, lane, 32), acc);
      s4v v;
#pragma unroll
      for (int r = 0; r < 4; ++r) v[r] = f2bf(fmaxf(acc[r], 0.f));
      int p = 16 * t + (lane & 15);
      int cb = 16 * w + 4 * (lane >> 4);
      *(s4v*)&x3p[(p << 6) + (((cb >> 2) ^ SW(p)) << 2)] = v;
    }
    __syncthreads();
    float vmax[2][4];
#pragma unroll
    for (int t = 0; t < 4; ++t) {
      s8v b0f = ldB_pc(x3p, t, lane, 0);
      s8v b1f = ldB_pc(x3p, t, lane, 32);
#pragma unroll
      for (int ot = 0; ot < 2; ++ot) {
        f4v acc; acc[0] = bias3[ot][0]; acc[1] = bias3[ot][1]; acc[2] = bias3[ot][2]; acc[3] = bias3[ot][3];
        acc = mm(w2f[ot][0], b0f, acc);
        acc = mm(w2f[ot][1], b1f, acc);
#pragma unroll
        for (int r = 0; r < 4; ++r)
          vmax[ot][r] = (t == 0) ? acc[r] : fmaxf(vmax[ot][r], acc[r]);
      }
    }
#pragma unroll
    for (int ot = 0; ot < 2; ++ot)
#pragma unroll
      for (int r = 0; r < 4; ++r) {
        float m = rowmax16(vmax[ot][r]);
        if ((lane & 15) == 15) {
          int o = 16 * (2 * w + ot) + 4 * (lane >> 4) + r;
          out[((size_t)b * 128 + o) * NS + s] = fmaxf(m, 0.f);
        }
      }
  }
}

extern "C" void kernel_launch(void* const* d_in, const int* in_sizes, int n_in,
                              void* d_out, int out_size, void* d_ws, size_t ws_size,
                              hipStream_t stream) {
  (void)in_sizes; (void)n_in; (void)out_size; (void)ws_size;
  const float* feature = (const float*)d_in[0];
  const float* coord = (const float*)d_in[1];
  const float* W0 = (const float*)d_in[2];  const float* b0 = (const float*)d_in[3];
  const float* g0 = (const float*)d_in[4];  const float* be0 = (const float*)d_in[5];
  const float* W1 = (const float*)d_in[6];  const float* b1 = (const float*)d_in[7];
  const float* g1 = (const float*)d_in[8];  const float* be1 = (const float*)d_in[9];
  const float* W2 = (const float*)d_in[10]; const float* b2 = (const float*)d_in[11];
  const float* g2 = (const float*)d_in[12]; const float* be2 = (const float*)d_in[13];
  float* out = (float*)d_out;
  float* ws = (float*)d_ws;
  float* newxyz = ws + OFF_NEWXYZ;
  float* x1 = ws + OFF_X1;
  float* stats = ws + OFF_STATS;
  float* fold = ws + OFF_FOLD;
  hipMemsetAsync(stats, 0, (size_t)NCOPY * ST_LEN * sizeof(float), stream);
  hipLaunchKernelGGL(k_fps, dim3(NB), dim3(512), 0, stream, coord, newxyz, out + OUTC_OFF);
  hipLaunchKernelGGL(k_group, dim3(4096), dim3(256), 0, stream, coord, feature, newxyz, x1, stats);
  hipLaunchKernelGGL(k_fold1, dim3(1), dim3(256), 0, stream, W0, b0, g0, be0, stats, fold);
  hipLaunchKernelGGL(k_pass2, dim3(512), dim3(256), 0, stream, x1, fold, stats);
  hipLaunchKernelGGL(k_fold2, dim3(1), dim3(256), 0, stream, W1, b1, g1, be1, stats, fold);
  hipLaunchKernelGGL(k_pass3, dim3(512), dim3(256), 0, stream, x1, fold, stats);
  hipLaunchKernelGGL(k_fold3, dim3(1), dim3(256), 0, stream, W2, b2, g2, be2, stats, fold);
  hipLaunchKernelGGL(k_final, dim3(2048), dim3(256), 0, stream, x1, fold, out);
}